// Round 15
// baseline (43.580 us; speedup 1.0000x reference)
//
#include <hip/hip_runtime.h>

#define NB 4096
#define DK 768
#define DKB 768          // bytes per row in fp8
#define SCALE_S 0.5295756522f

typedef float f32x4 __attribute__((ext_vector_type(4)));
typedef int i32x4 __attribute__((ext_vector_type(4)));
typedef int i32x8 __attribute__((ext_vector_type(8)));

// ---- ws layout (bytes) ----
#define OFF_XQ      0u            // 4096*768 fp8 = 3145728
#define OFF_YQ      3145728u
#define OFF_ROWPM   12582912u     // 32*4096 f32 = 512KB
#define OFF_ROWPS   13107200u
#define OFF_COLPM   13631488u     // 16*4096 f32
#define OFF_COLPS   14155776u
#define OFF_BITS    14712832u     // 4096 u32
#define OFF_CSPART  14729216u     // 16*32 int
#define OFF_DOTP    14731264u     // 512 f32
#define OFF_WSUM    14733312u     // 32 f32

// f32 -> OCP e4m3fn, RNE, saturate to 448, subnormal-correct
static __device__ __forceinline__ unsigned char f2e4m3(float f) {
  union { float f; unsigned u; } x; x.f = f;
  unsigned s = (x.u >> 24) & 0x80u;
  x.u &= 0x7FFFFFFFu;
  float af = x.f;
  if (af >= 448.f) return (unsigned char)(s | 0x7Eu);
  int e = (int)(x.u >> 23) - 127;
  int eq = e < -6 ? -6 : e;
  float scale = __int_as_float((unsigned)((3 - eq) + 127) << 23);  // 2^(3-eq)
  int q = (int)rintf(af * scale);                                  // [0,16)
  if (q == 16) { q = 8; ++eq; }
  if (e < -6) return (unsigned char)(s | (unsigned)q);             // subnormal
  return (unsigned char)(s | (((unsigned)(eq + 7)) << 3) | ((unsigned)(q - 8)));
}

static __device__ __forceinline__ void gload16(const void* g, void* l) {
  __builtin_amdgcn_global_load_lds(
      (const __attribute__((address_space(1))) unsigned int*)g,
      (__attribute__((address_space(3))) unsigned int*)l,
      16, 0, 0);
}

// K1: fused prep. Blocks 0..15: pack label bits + colsum partials.
// Blocks 16..: fp32 -> e4m3 conversion of X and Y (grid-stride).
__global__ void k_prep(const int* __restrict__ labels, unsigned* __restrict__ bits,
                       int* __restrict__ csPart,
                       const float* __restrict__ X, const float* __restrict__ Y,
                       unsigned char* __restrict__ Xq, unsigned char* __restrict__ Yq) {
  int t = threadIdx.x;
  if (blockIdx.x < 16) {
    __shared__ int cs[32];
    if (t < 32) cs[t] = 0;
    __syncthreads();
    int i = blockIdx.x * 256 + t;
    const int* row = labels + (size_t)i * 32;
    unsigned b = 0;
#pragma unroll
    for (int j = 0; j < 32; ++j) if (row[j] != 0) b |= (1u << j);
    bits[i] = b;
#pragma unroll
    for (int j = 0; j < 32; ++j) if (b & (1u << j)) atomicAdd(&cs[j], 1);
    __syncthreads();
    if (t < 32) csPart[blockIdx.x * 32 + t] = cs[t];
  } else {
    const int N4 = (NB * DK) / 4;  // 786432
    const int stride = (gridDim.x - 16) * 256;
    for (int idx = (blockIdx.x - 16) * 256 + t; idx < 2 * N4; idx += stride) {
      float4 v; unsigned* dst;
      if (idx < N4) { v = ((const float4*)X)[idx]; dst = (unsigned*)Xq + idx; }
      else          { v = ((const float4*)Y)[idx - N4]; dst = (unsigned*)Yq + (idx - N4); }
      unsigned p = (unsigned)f2e4m3(v.x) | ((unsigned)f2e4m3(v.y) << 8) |
                   ((unsigned)f2e4m3(v.z) << 16) | ((unsigned)f2e4m3(v.w) << 24);
      *dst = p;
    }
  }
}

// K4: 256x128 MX-fp8 GEMM, grid 512 = 2 blocks/CU (cross-block overlap, m114),
// 512 threads / 8 waves (4x2 wave grid, 64x64 out each, acc[4][4]). BK=128
// (6 K-tiles), single-buffered 48KB LDS: sync -> stage -> sync -> compute.
// Block A's stage-drain overlaps block B's compute. Verified fp8 fragment map
// + 16B-granule XOR-row&7 swizzle (R12/R14 refcheck). Fused epilogue.
// LDS: A[256r][128B] at 0, B[128r][128B] at 32768. Total 48KB + epilogue reuse.

// load a 32B k-chunk fragment (two swizzled b128 reads) into v8i32
#define LOADFRAG(DST, BASE) do { \
    i32x4 _lo = *(const i32x4*)((BASE) + offg0); \
    i32x4 _hi = *(const i32x4*)((BASE) + offg1); \
    DST[0] = _lo[0]; DST[1] = _lo[1]; DST[2] = _lo[2]; DST[3] = _lo[3]; \
    DST[4] = _hi[0]; DST[5] = _hi[1]; DST[6] = _hi[2]; DST[7] = _hi[3]; \
  } while (0)

#define STAGE_T(KT) do { \
    const unsigned char* _ga = pA + (size_t)(KT) * 128; \
    const unsigned char* _gb = pB + (size_t)(KT) * 128; \
    gload16(_ga,                     ldsw); \
    gload16(_ga + (size_t)64  * DKB, ldsw + 8192); \
    gload16(_ga + (size_t)128 * DKB, ldsw + 16384); \
    gload16(_ga + (size_t)192 * DKB, ldsw + 24576); \
    gload16(_gb,                     ldsw + 32768); \
    gload16(_gb + (size_t)64  * DKB, ldsw + 40960); \
  } while (0)

__launch_bounds__(512, 4)
__global__ void k_gemm(const unsigned char* __restrict__ Xq,
                       const unsigned char* __restrict__ Yq,
                       const unsigned* __restrict__ bits,
                       float* __restrict__ rowPM, float* __restrict__ rowPS,
                       float* __restrict__ colPM, float* __restrict__ colPS,
                       float* __restrict__ dotPart) {
  extern __shared__ char lds[];

  const int t = threadIdx.x;             // 0..511
  const int wave = t >> 6, lane = t & 63;
  const int wr = wave >> 1, wc = wave & 1;   // 4x2 wave grid, 64x64 out each

  // bijective XCD-aware swizzle: 512 blocks; each XCD gets a 4rb x 16cb patch
  const int bid = blockIdx.x;
  const int xcd = bid & 7, loc = bid >> 3;          // loc 0..63
  const int rb = (xcd & 3) * 4 + (loc >> 4);        // 0..15 (256-row panels)
  const int cb = (xcd >> 2) * 16 + (loc & 15);      // 0..31 (128-col panels)

  // staging: each wave stages A rows wave*8+(lane>>3) (+64 per issue, 4 issues)
  // and B rows likewise (2 issues). Source granule pre-swizzled: g=(l&7)^(l>>3).
  const int g0 = ((lane & 7) ^ (lane >> 3)) * 16;
  const int srow = wave * 8 + (lane >> 3);
  const unsigned char* pA = Xq + (size_t)(rb * 256 + srow) * DKB + g0;
  const unsigned char* pB = Yq + (size_t)(cb * 128 + srow) * DKB + g0;
  char* ldsw = lds + wave * 1024;

  // fragment read offsets (bytes); row&7 == lrow&7 for all m,n (rows step 16)
  const int lrow = lane & 15;
  const int s7 = lrow & 7;
  const int gp = (lane >> 4) * 2;
  const int offg0 = ((gp) ^ s7) * 16;
  const int offg1 = ((gp + 1) ^ s7) * 16;
  const int rowA0 = (wr * 64 + lrow) * 128;          // + m*2048, m=0..3
  const int rowB0 = 32768 + (wc * 64 + lrow) * 128;  // + n*2048, n=0..3

  f32x4 acc[4][4];
#pragma unroll
  for (int m = 0; m < 4; ++m)
#pragma unroll
    for (int n = 0; n < 4; ++n) acc[m][n] = (f32x4){0.f, 0.f, 0.f, 0.f};

#pragma unroll 1
  for (int kt = 0; kt < 6; ++kt) {
    __syncthreads();            // prior tile's reads complete before overwrite
    STAGE_T(kt);
    __syncthreads();            // vmcnt(0)+barrier: tile staged
    i32x8 bF[4];
#pragma unroll
    for (int n = 0; n < 4; ++n) LOADFRAG(bF[n], lds + rowB0 + n * 2048);
    __builtin_amdgcn_s_setprio(1);
#pragma unroll
    for (int m = 0; m < 4; ++m) {
      i32x8 aF;
      LOADFRAG(aF, lds + rowA0 + m * 2048);
#pragma unroll
      for (int n = 0; n < 4; ++n)
        acc[m][n] = __builtin_amdgcn_mfma_scale_f32_16x16x128_f8f6f4(
            aF, bF[n], acc[m][n], 0, 0, 0, 127, 0, 127);
    }
    __builtin_amdgcn_s_setprio(0);
  }
  __syncthreads();   // all LDS reads done before reuse as reduction scratch

  // ---- epilogue (C/D: col=lane&15, row=(lane>>4)*4+r — dtype-independent) ----
  float* fb    = (float*)lds;
  float* redM  = fb;                       // [256][2]
  float* redS  = fb + 512;                 // [256][2]
  float* redM2 = fb + 1024;                // [128][4]
  float* redS2 = fb + 1536;                // [128][4]
  unsigned* bR = (unsigned*)(fb + 2048);   // 256
  unsigned* bC = bR + 256;                 // 128
  float* wred  = (float*)(bC + 128);       // 8

  if (t < 256) bR[t] = bits[rb * 256 + t];
  else if (t < 384) bC[t - 256] = bits[cb * 128 + (t - 256)];

  // (a) row partials over this wave's 64 cols
#pragma unroll
  for (int m = 0; m < 4; ++m) {
#pragma unroll
    for (int r = 0; r < 4; ++r) {
      float v0 = SCALE_S * acc[m][0][r];
      float v1 = SCALE_S * acc[m][1][r];
      float v2 = SCALE_S * acc[m][2][r];
      float v3 = SCALE_S * acc[m][3][r];
      float mx = fmaxf(fmaxf(v0, v1), fmaxf(v2, v3));
#pragma unroll
      for (int off = 1; off < 16; off <<= 1) mx = fmaxf(mx, __shfl_xor(mx, off));
      float sm = __expf(v0 - mx) + __expf(v1 - mx) + __expf(v2 - mx) + __expf(v3 - mx);
#pragma unroll
      for (int off = 1; off < 16; off <<= 1) sm += __shfl_xor(sm, off);
      if ((lane & 15) == 0) {
        int row = wr * 64 + m * 16 + (lane >> 4) * 4 + r;
        redM[row * 2 + wc] = mx; redS[row * 2 + wc] = sm;
      }
    }
  }
  // col partials over this wave's 64 rows
#pragma unroll
  for (int n = 0; n < 4; ++n) {
    float mx = -3.0e38f;
#pragma unroll
    for (int m = 0; m < 4; ++m)
#pragma unroll
      for (int r = 0; r < 4; ++r) mx = fmaxf(mx, SCALE_S * acc[m][n][r]);
    mx = fmaxf(mx, __shfl_xor(mx, 16));
    mx = fmaxf(mx, __shfl_xor(mx, 32));
    float sm = 0.f;
#pragma unroll
    for (int m = 0; m < 4; ++m)
#pragma unroll
      for (int r = 0; r < 4; ++r) sm += __expf(SCALE_S * acc[m][n][r] - mx);
    sm += __shfl_xor(sm, 16);
    sm += __shfl_xor(sm, 32);
    if (lane < 16) {
      int col = wc * 64 + n * 16 + lane;
      redM2[col * 4 + wr] = mx; redS2[col * 4 + wr] = sm;
    }
  }
  __syncthreads();

  // (b) W.C tile sum: popcount(bits_row & bits_col) * C (unscaled)
  float ws = 0.f;
  {
    unsigned bc[4];
#pragma unroll
    for (int n = 0; n < 4; ++n) bc[n] = bC[wc * 64 + n * 16 + (lane & 15)];
#pragma unroll
    for (int m = 0; m < 4; ++m) {
#pragma unroll
      for (int r = 0; r < 4; ++r) {
        unsigned br = bR[wr * 64 + m * 16 + (lane >> 4) * 4 + r];
#pragma unroll
        for (int n = 0; n < 4; ++n)
          ws += (float)__popc(br & bc[n]) * acc[m][n][r];
      }
    }
  }
#pragma unroll
  for (int off = 32; off; off >>= 1) ws += __shfl_xor(ws, off);
  if (lane == 0) wred[wave] = ws;

  // combine partials -> per-(block,row/col) (M,S)
  if (t < 256) {
    float m0 = redM[t * 2 + 0], m1 = redM[t * 2 + 1];
    float M = fmaxf(m0, m1);
    float S = redS[t * 2 + 0] * __expf(m0 - M) + redS[t * 2 + 1] * __expf(m1 - M);
    rowPM[(size_t)cb * NB + rb * 256 + t] = M;
    rowPS[(size_t)cb * NB + rb * 256 + t] = S;
  } else if (t < 384) {
    int c = t - 256;
    float M = fmaxf(fmaxf(redM2[c * 4 + 0], redM2[c * 4 + 1]),
                    fmaxf(redM2[c * 4 + 2], redM2[c * 4 + 3]));
    float S = 0.f;
#pragma unroll
    for (int k = 0; k < 4; ++k) S += redS2[c * 4 + k] * __expf(redM2[c * 4 + k] - M);
    colPM[(size_t)rb * NB + cb * 128 + c] = M;
    colPS[(size_t)rb * NB + cb * 128 + c] = S;
  }
  __syncthreads();
  if (t == 0) {
    float s = 0.f;
#pragma unroll
    for (int w = 0; w < 8; ++w) s += wred[w];
    dotPart[bid] = s;
  }
}

// K5: combine lse partials (rows: 32, cols: 16) AND fold in the rw-weighted sum
__global__ void k_tail(const float* __restrict__ rowPM, const float* __restrict__ rowPS,
                       const float* __restrict__ colPM, const float* __restrict__ colPS,
                       const unsigned* __restrict__ bits, const int* __restrict__ csPart,
                       float* __restrict__ wsum) {
  __shared__ int cs[32];
  __shared__ float red[256];
  int t = threadIdx.x, b = blockIdx.x;
  if (t < 32) {
    int s = 0;
    for (int k = 0; k < 16; ++k) s += csPart[k * 32 + t];
    cs[t] = s;
  }
  __syncthreads();
  int g = b * 256 + t;   // 0..8191
  int i; float M = -3.0e38f, S = 0.f;
  if (g < NB) {
    i = g;
#pragma unroll
    for (int c = 0; c < 32; ++c) M = fmaxf(M, rowPM[(size_t)c * NB + i]);
#pragma unroll
    for (int c = 0; c < 32; ++c) S += rowPS[(size_t)c * NB + i] * __expf(rowPM[(size_t)c * NB + i] - M);
  } else {
    i = g - NB;
#pragma unroll
    for (int c = 0; c < 16; ++c) M = fmaxf(M, colPM[(size_t)c * NB + i]);
#pragma unroll
    for (int c = 0; c < 16; ++c) S += colPS[(size_t)c * NB + i] * __expf(colPM[(size_t)c * NB + i] - M);
  }
  float lse = M + __logf(S);
  unsigned bb = bits[i];
  int rw = 0;
#pragma unroll
  for (int j = 0; j < 32; ++j) if (bb & (1u << j)) rw += cs[j];
  red[t] = (float)rw * lse;
  __syncthreads();
  for (int s = 128; s; s >>= 1) {
    if (t < s) red[t] += red[t + s];
    __syncthreads();
  }
  if (t == 0) wsum[b] = red[0];
}

// K7: finalize scalar loss from 32 wsum + 512 dot partials
__global__ void k_final(const float* __restrict__ wsum, const float* __restrict__ dotPart,
                        float* __restrict__ out) {
  __shared__ double red[256];
  int t = threadIdx.x;
  double a = 0.0;
  if (t < 32) a += (double)wsum[t];
  a -= 2.0 * (double)SCALE_S * ((double)dotPart[t] + (double)dotPart[t + 256]);
  red[t] = a;
  __syncthreads();
  for (int s = 128; s; s >>= 1) {
    if (t < s) red[t] += red[t + s];
    __syncthreads();
  }
  if (t == 0) out[0] = (float)(red[0] / (2.0 * (double)NB * 32.0));
}

extern "C" void kernel_launch(void* const* d_in, const int* in_sizes, int n_in,
                              void* d_out, int out_size, void* d_ws, size_t ws_size,
                              hipStream_t stream) {
  const float* X = (const float*)d_in[0];
  const float* Y = (const float*)d_in[1];
  const int* labels = (const int*)d_in[2];
  char* ws = (char*)d_ws;

  unsigned char* Xq = (unsigned char*)(ws + OFF_XQ);
  unsigned char* Yq = (unsigned char*)(ws + OFF_YQ);
  float* rowPM = (float*)(ws + OFF_ROWPM);
  float* rowPS = (float*)(ws + OFF_ROWPS);
  float* colPM = (float*)(ws + OFF_COLPM);
  float* colPS = (float*)(ws + OFF_COLPS);
  unsigned* bits = (unsigned*)(ws + OFF_BITS);
  int* csPart = (int*)(ws + OFF_CSPART);
  float* dotPart = (float*)(ws + OFF_DOTP);
  float* wsum = (float*)(ws + OFF_WSUM);

  (void)hipFuncSetAttribute((const void*)k_gemm,
                            hipFuncAttributeMaxDynamicSharedMemorySize, 49152);

  k_prep<<<1040, 256, 0, stream>>>(labels, bits, csPart, X, Y, Xq, Yq);
  k_gemm<<<512, 512, 49152, stream>>>(Xq, Yq, bits, rowPM, rowPS, colPM, colPS, dotPart);
  k_tail<<<32, 256, 0, stream>>>(rowPM, rowPS, colPM, colPS, bits, csPart, wsum);
  k_final<<<1, 256, 0, stream>>>(wsum, dotPart, (float*)d_out);
}

// Round 16
// 36.853 us; speedup vs baseline: 1.1826x; 1.1826x over previous
//
#include <hip/hip_runtime.h>

#define NB 4096
#define DK 768
#define DKB4 384         // bytes per row in fp4
#define SCALE_S 0.5295756522f

typedef float f32x4 __attribute__((ext_vector_type(4)));
typedef int i32x4 __attribute__((ext_vector_type(4)));
typedef int i32x8 __attribute__((ext_vector_type(8)));

// ---- ws layout (bytes) ----
#define OFF_XQ      0u            // 4096*384 fp4 = 1572864
#define OFF_YQ      3145728u
#define OFF_ROWPM   12582912u     // 16*4096 f32
#define OFF_ROWPS   13107200u
#define OFF_COLPM   13631488u
#define OFF_COLPS   14155776u
#define OFF_BITS    14712832u     // 4096 u32
#define OFF_CSPART  14729216u     // 16*32 int
#define OFF_DOTP    14731264u     // 256 f32
#define OFF_WSUM    14735360u     // 32 f32

// f32 -> fp4 e2m1 (values {0,.5,1,1.5,2,3,4,6}), nearest
static __device__ __forceinline__ unsigned f2e2m1(float f) {
  unsigned s = f < 0.f ? 8u : 0u;
  float a = fabsf(f);
  unsigned c;
  if      (a < 0.25f) c = 0;
  else if (a < 0.75f) c = 1;
  else if (a < 1.25f) c = 2;
  else if (a < 1.75f) c = 3;
  else if (a < 2.50f) c = 4;
  else if (a < 3.50f) c = 5;
  else if (a < 5.00f) c = 6;
  else                c = 7;
  return s | c;
}

static __device__ __forceinline__ void gload16(const void* g, void* l) {
  __builtin_amdgcn_global_load_lds(
      (const __attribute__((address_space(1))) unsigned int*)g,
      (__attribute__((address_space(3))) unsigned int*)l,
      16, 0, 0);
}

// K1: fused prep. Blocks 0..15: pack label bits + colsum partials.
// Blocks 16..: fp32 -> e2m1 fp4 conversion of X and Y (grid-stride, 8 vals/u32).
__global__ void k_prep(const int* __restrict__ labels, unsigned* __restrict__ bits,
                       int* __restrict__ csPart,
                       const float* __restrict__ X, const float* __restrict__ Y,
                       unsigned* __restrict__ Xq, unsigned* __restrict__ Yq) {
  int t = threadIdx.x;
  if (blockIdx.x < 16) {
    __shared__ int cs[32];
    if (t < 32) cs[t] = 0;
    __syncthreads();
    int i = blockIdx.x * 256 + t;
    const int* row = labels + (size_t)i * 32;
    unsigned b = 0;
#pragma unroll
    for (int j = 0; j < 32; ++j) if (row[j] != 0) b |= (1u << j);
    bits[i] = b;
#pragma unroll
    for (int j = 0; j < 32; ++j) if (b & (1u << j)) atomicAdd(&cs[j], 1);
    __syncthreads();
    if (t < 32) csPart[blockIdx.x * 32 + t] = cs[t];
  } else {
    const int N8 = (NB * DK) / 8;  // 393216 u32 outputs per matrix
    const int stride = (gridDim.x - 16) * 256;
    for (int idx = (blockIdx.x - 16) * 256 + t; idx < 2 * N8; idx += stride) {
      const float4* src; unsigned* dst; int base;
      if (idx < N8) { base = idx;      src = (const float4*)X; dst = Xq + base; }
      else          { base = idx - N8; src = (const float4*)Y; dst = Yq + base; }
      float4 v0 = src[base * 2], v1 = src[base * 2 + 1];
      unsigned p = f2e2m1(v0.x)        | (f2e2m1(v0.y) << 4)  |
                   (f2e2m1(v0.z) << 8) | (f2e2m1(v0.w) << 12) |
                   (f2e2m1(v1.x) << 16)| (f2e2m1(v1.y) << 20) |
                   (f2e2m1(v1.z) << 24)| (f2e2m1(v1.w) << 28);
      *dst = p;
    }
  }
}

// K4: 256x256 MX-fp4 GEMM, R14 structure: 1024 threads / 16 waves (4 waves/SIMD),
// wave grid 4x4 (64x64 out each, acc[4][4]). BK=128 elems = 64B/row (6 K-tiles),
// 2x32KB LDS double-buffer, prefetch kt+1 before compute kt, one __syncthreads
// per tile. 16x16x128 f8f6f4 with cbsz=blgp=4 (fp4), unity e8m0 scales (127).
// Swizzle: 16B granule g at row r holds global granule g ^ ((r>>1)&3) — 2-way-
// free banks; stage pre-swizzles global source (linear gload_lds dest, rule #21).
// K-permutation of nibble/lane order is A/B-symmetric -> dot invariant (unity
// scales), so only e2m1 values and formats must be absolutely right.
// LDS buf b (32KB): A[256r][64B] at b*32768, B at +16384.

#define STAGE_T(DBUF, KT) do { \
    char* _la = lds + (DBUF) * 32768 + wave * 1024; \
    gload16(pA + (size_t)(KT) * 64, _la); \
    gload16(pB + (size_t)(KT) * 64, _la + 16384); \
  } while (0)

__launch_bounds__(1024)
__global__ void k_gemm(const unsigned char* __restrict__ Xq,
                       const unsigned char* __restrict__ Yq,
                       const unsigned* __restrict__ bits,
                       float* __restrict__ rowPM, float* __restrict__ rowPS,
                       float* __restrict__ colPM, float* __restrict__ colPS,
                       float* __restrict__ dotPart) {
  extern __shared__ char lds[];

  const int t = threadIdx.x;             // 0..1023
  const int wave = t >> 6, lane = t & 63;
  const int wr = wave >> 2, wc = wave & 3;   // 4x4 wave grid, 64x64 out each

  // bijective XCD-aware swizzle: each XCD gets a 4rb x 8cb sub-grid (16x16 grid)
  const int bid = blockIdx.x;
  const int xcd = bid & 7, loc = bid >> 3;
  const int rb = (xcd & 3) * 4 + (loc >> 3);
  const int cb = (xcd >> 2) * 8 + (loc & 7);

  // staging: wave w covers rows w*16 + (lane>>2) of both A and B (16 rows/wave);
  // lane granule (lane&3), source pre-swizzled by ((row>>1)&3) = ((lane>>3)&3)
  const int gs = ((lane & 3) ^ ((lane >> 3) & 3)) * 16;
  const int srow = wave * 16 + (lane >> 2);
  const unsigned char* pA = Xq + (size_t)(rb * 256 + srow) * DKB4 + gs;
  const unsigned char* pB = Yq + (size_t)(cb * 256 + srow) * DKB4 + gs;

  // fragment read offsets (bytes); (row>>1)&3 == (lrow>>1)&3 for all m,n
  const int lrow = lane & 15;
  const int offg = (((lane >> 4) ^ ((lrow >> 1) & 3))) * 16;
  const int rowA0 = (wr * 64 + lrow) * 64 + offg;           // + m*1024
  const int rowB0 = 16384 + (wc * 64 + lrow) * 64 + offg;   // + n*1024

  f32x4 acc[4][4];
#pragma unroll
  for (int m = 0; m < 4; ++m)
#pragma unroll
    for (int n = 0; n < 4; ++n) acc[m][n] = (f32x4){0.f, 0.f, 0.f, 0.f};

  // prologue: stage tile0 into buf0
  STAGE_T(0, 0);
  asm volatile("s_waitcnt vmcnt(0)" ::: "memory");
  __builtin_amdgcn_s_barrier();

#pragma unroll 1
  for (int kt = 0; kt < 6; ++kt) {
    const int cur = kt & 1;
    if (kt < 5) STAGE_T(cur ^ 1, kt + 1);
    const char* _c = lds + cur * 32768;
    i32x8 bF[4];
#pragma unroll
    for (int n = 0; n < 4; ++n) {
      i32x4 v = *(const i32x4*)(_c + rowB0 + n * 1024);
      bF[n][0] = v[0]; bF[n][1] = v[1]; bF[n][2] = v[2]; bF[n][3] = v[3];
      bF[n][4] = 0; bF[n][5] = 0; bF[n][6] = 0; bF[n][7] = 0;
    }
    __builtin_amdgcn_s_setprio(1);
#pragma unroll
    for (int m = 0; m < 4; ++m) {
      i32x4 va = *(const i32x4*)(_c + rowA0 + m * 1024);
      i32x8 aF;
      aF[0] = va[0]; aF[1] = va[1]; aF[2] = va[2]; aF[3] = va[3];
      aF[4] = 0; aF[5] = 0; aF[6] = 0; aF[7] = 0;
#pragma unroll
      for (int n = 0; n < 4; ++n)
        acc[m][n] = __builtin_amdgcn_mfma_scale_f32_16x16x128_f8f6f4(
            aF, bF[n], acc[m][n], 4, 4, 0, 127, 0, 127);
    }
    __builtin_amdgcn_s_setprio(0);
    __syncthreads();   // drains vmcnt(0)+lgkmcnt(0): tile kt+1 landed, buf safe
  }

  // ---- epilogue (C/D: col=lane&15, row=(lane>>4)*4+r — dtype-independent) ----
  float* fb    = (float*)lds;
  float* redM  = fb;                       // [256][4]
  float* redS  = fb + 1024;                // [256][4]
  float* redM2 = fb + 2048;                // [256][4]
  float* redS2 = fb + 3072;                // [256][4]
  unsigned* bR = (unsigned*)(fb + 4096);   // 256
  unsigned* bC = bR + 256;                 // 256
  float* wred  = (float*)(bC + 256);       // 16

  if (t < 256) bR[t] = bits[rb * 256 + t];
  else if (t < 512) bC[t - 256] = bits[cb * 256 + (t - 256)];

  // (a) row partials over this wave's 64 cols
#pragma unroll
  for (int m = 0; m < 4; ++m) {
#pragma unroll
    for (int r = 0; r < 4; ++r) {
      float v0 = SCALE_S * acc[m][0][r];
      float v1 = SCALE_S * acc[m][1][r];
      float v2 = SCALE_S * acc[m][2][r];
      float v3 = SCALE_S * acc[m][3][r];
      float mx = fmaxf(fmaxf(v0, v1), fmaxf(v2, v3));
#pragma unroll
      for (int off = 1; off < 16; off <<= 1) mx = fmaxf(mx, __shfl_xor(mx, off));
      float sm = __expf(v0 - mx) + __expf(v1 - mx) + __expf(v2 - mx) + __expf(v3 - mx);
#pragma unroll
      for (int off = 1; off < 16; off <<= 1) sm += __shfl_xor(sm, off);
      if ((lane & 15) == 0) {
        int row = wr * 64 + m * 16 + (lane >> 4) * 4 + r;
        redM[row * 4 + wc] = mx; redS[row * 4 + wc] = sm;
      }
    }
  }
  // col partials over this wave's 64 rows
#pragma unroll
  for (int n = 0; n < 4; ++n) {
    float mx = -3.0e38f;
#pragma unroll
    for (int m = 0; m < 4; ++m)
#pragma unroll
      for (int r = 0; r < 4; ++r) mx = fmaxf(mx, SCALE_S * acc[m][n][r]);
    mx = fmaxf(mx, __shfl_xor(mx, 16));
    mx = fmaxf(mx, __shfl_xor(mx, 32));
    float sm = 0.f;
#pragma unroll
    for (int m = 0; m < 4; ++m)
#pragma unroll
      for (int r = 0; r < 4; ++r) sm += __expf(SCALE_S * acc[m][n][r] - mx);
    sm += __shfl_xor(sm, 16);
    sm += __shfl_xor(sm, 32);
    if (lane < 16) {
      int col = wc * 64 + n * 16 + lane;
      redM2[col * 4 + wr] = mx; redS2[col * 4 + wr] = sm;
    }
  }
  __syncthreads();

  // (b) W.C tile sum: popcount(bits_row & bits_col) * C (unscaled)
  float ws = 0.f;
  {
    unsigned bc[4];
#pragma unroll
    for (int n = 0; n < 4; ++n) bc[n] = bC[wc * 64 + n * 16 + (lane & 15)];
#pragma unroll
    for (int m = 0; m < 4; ++m) {
#pragma unroll
      for (int r = 0; r < 4; ++r) {
        unsigned br = bR[wr * 64 + m * 16 + (lane >> 4) * 4 + r];
#pragma unroll
        for (int n = 0; n < 4; ++n)
          ws += (float)__popc(br & bc[n]) * acc[m][n][r];
      }
    }
  }
#pragma unroll
  for (int off = 32; off; off >>= 1) ws += __shfl_xor(ws, off);
  if (lane == 0) wred[wave] = ws;

  // combine partials -> per-(block,row/col) (M,S)
  if (t < 256) {
    float M = fmaxf(fmaxf(redM[t * 4 + 0], redM[t * 4 + 1]),
                    fmaxf(redM[t * 4 + 2], redM[t * 4 + 3]));
    float S = 0.f;
#pragma unroll
    for (int k = 0; k < 4; ++k) S += redS[t * 4 + k] * __expf(redM[t * 4 + k] - M);
    rowPM[(size_t)cb * NB + rb * 256 + t] = M;
    rowPS[(size_t)cb * NB + rb * 256 + t] = S;
  } else if (t < 512) {
    int c = t - 256;
    float M = fmaxf(fmaxf(redM2[c * 4 + 0], redM2[c * 4 + 1]),
                    fmaxf(redM2[c * 4 + 2], redM2[c * 4 + 3]));
    float S = 0.f;
#pragma unroll
    for (int k = 0; k < 4; ++k) S += redS2[c * 4 + k] * __expf(redM2[c * 4 + k] - M);
    colPM[(size_t)rb * NB + cb * 256 + c] = M;
    colPS[(size_t)rb * NB + cb * 256 + c] = S;
  }
  __syncthreads();
  if (t == 0) {
    float s = 0.f;
#pragma unroll
    for (int w = 0; w < 16; ++w) s += wred[w];
    dotPart[bid] = s;
  }
}

// K5: combine 16 lse partials per row/col AND fold in the rw-weighted sum
__global__ void k_tail(const float* __restrict__ rowPM, const float* __restrict__ rowPS,
                       const float* __restrict__ colPM, const float* __restrict__ colPS,
                       const unsigned* __restrict__ bits, const int* __restrict__ csPart,
                       float* __restrict__ wsum) {
  __shared__ int cs[32];
  __shared__ float red[256];
  int t = threadIdx.x, b = blockIdx.x;
  if (t < 32) {
    int s = 0;
    for (int k = 0; k < 16; ++k) s += csPart[k * 32 + t];
    cs[t] = s;
  }
  __syncthreads();
  int g = b * 256 + t;   // 0..8191
  int i; float M = -3.0e38f, S = 0.f;
  if (g < NB) {
    i = g;
#pragma unroll
    for (int c = 0; c < 16; ++c) M = fmaxf(M, rowPM[(size_t)c * NB + i]);
#pragma unroll
    for (int c = 0; c < 16; ++c) S += rowPS[(size_t)c * NB + i] * __expf(rowPM[(size_t)c * NB + i] - M);
  } else {
    i = g - NB;
#pragma unroll
    for (int c = 0; c < 16; ++c) M = fmaxf(M, colPM[(size_t)c * NB + i]);
#pragma unroll
    for (int c = 0; c < 16; ++c) S += colPS[(size_t)c * NB + i] * __expf(colPM[(size_t)c * NB + i] - M);
  }
  float lse = M + __logf(S);
  unsigned bb = bits[i];
  int rw = 0;
#pragma unroll
  for (int j = 0; j < 32; ++j) if (bb & (1u << j)) rw += cs[j];
  red[t] = (float)rw * lse;
  __syncthreads();
  for (int s = 128; s; s >>= 1) {
    if (t < s) red[t] += red[t + s];
    __syncthreads();
  }
  if (t == 0) wsum[b] = red[0];
}

// K7: finalize scalar loss from 32 wsum + 256 dot partials
__global__ void k_final(const float* __restrict__ wsum, const float* __restrict__ dotPart,
                        float* __restrict__ out) {
  __shared__ double red[256];
  int t = threadIdx.x;
  double a = 0.0;
  if (t < 32) a += (double)wsum[t];
  a -= 2.0 * (double)SCALE_S * (double)dotPart[t];
  red[t] = a;
  __syncthreads();
  for (int s = 128; s; s >>= 1) {
    if (t < s) red[t] += red[t + s];
    __syncthreads();
  }
  if (t == 0) out[0] = (float)(red[0] / (2.0 * (double)NB * 32.0));
}

extern "C" void kernel_launch(void* const* d_in, const int* in_sizes, int n_in,
                              void* d_out, int out_size, void* d_ws, size_t ws_size,
                              hipStream_t stream) {
  const float* X = (const float*)d_in[0];
  const float* Y = (const float*)d_in[1];
  const int* labels = (const int*)d_in[2];
  char* ws = (char*)d_ws;

  unsigned* Xq = (unsigned*)(ws + OFF_XQ);
  unsigned* Yq = (unsigned*)(ws + OFF_YQ);
  float* rowPM = (float*)(ws + OFF_ROWPM);
  float* rowPS = (float*)(ws + OFF_ROWPS);
  float* colPM = (float*)(ws + OFF_COLPM);
  float* colPS = (float*)(ws + OFF_COLPS);
  unsigned* bits = (unsigned*)(ws + OFF_BITS);
  int* csPart = (int*)(ws + OFF_CSPART);
  float* dotPart = (float*)(ws + OFF_DOTP);
  float* wsum = (float*)(ws + OFF_WSUM);

  (void)hipFuncSetAttribute((const void*)k_gemm,
                            hipFuncAttributeMaxDynamicSharedMemorySize, 65536);

  k_prep<<<1040, 256, 0, stream>>>(labels, bits, csPart, X, Y, Xq, Yq);
  k_gemm<<<256, 1024, 65536, stream>>>((const unsigned char*)Xq, (const unsigned char*)Yq,
                                       bits, rowPM, rowPS, colPM, colPS, dotPart);
  k_tail<<<32, 256, 0, stream>>>(rowPM, rowPS, colPM, colPS, bits, csPart, wsum);
  k_final<<<1, 256, 0, stream>>>(wsum, dotPart, (float*)d_out);
}